// Round 9
// baseline (169.946 us; speedup 1.0000x reference)
//
#include <hip/hip_runtime.h>
#include <math.h>

#define GAMMA 0.25f
constexpr int B_ = 8, Q_ = 64, N_ = 8192, K_ = 512, C_ = 256;

typedef __attribute__((ext_vector_type(8))) short bf16x8;
typedef __attribute__((ext_vector_type(4))) float f32x4;

static __device__ inline short f2bf(float x) {   // RNE float->bf16 bits
    union { float f; unsigned u; } v; v.f = x;
    unsigned r = (v.u + 0x7fffu + ((v.u >> 16) & 1u)) >> 16;
    return (short)r;
}
// pack trunc(lo),trunc(hi) bf16 into one dword via v_perm_b32 (1 instr)
static __device__ inline unsigned pack2(float lo, float hi) {
    return __builtin_amdgcn_perm(__float_as_uint(hi), __float_as_uint(lo), 0x07060302u);
}

// ---------------------------------------------------------------------------
// VQ: barrier-free, LDS-free, scratch-free. Block = 4 waves x 32 items.
// B-tiles read as fp32 straight from emb (128 KB, L2-hot), trunc-packed to
// bf16 in-register; e2 computed on the fly (fp32 squares + 2 shfl_xor over
// quad lanes). A holds bf16(-2z) RNE; C seeded with e2 so D = e2 - 2<z,e>.
// ---------------------------------------------------------------------------
__global__ __launch_bounds__(256, 2) void vq_kernel(const float* __restrict__ ze,
                                                    const float* __restrict__ emb,
                                                    float* __restrict__ out)
{
    const int tid  = threadIdx.x;
    const int lane = tid & 63;
    const int w    = tid >> 6;
    const int n16  = lane & 15;
    const int quad = lane >> 4;

    const int ib0 = blockIdx.x * 128;        // 128-aligned flat (b,n) => b uniform
    const int b   = ib0 >> 13;
    const int n0  = ib0 & (N_ - 1);
    const float* zb = ze + (size_t)b * Q_ * N_;

    // A fragments: afrag[u][s][j] = bf16(-2 * z[q = s*32+quad*8+j][item n16]) (RNE)
    bf16x8 afrag[2][2];
    float zsq = 0.f;
    #pragma unroll
    for (int u = 0; u < 2; ++u) {
        const int nn = n0 + u * 64 + w * 16 + n16;
        #pragma unroll
        for (int s = 0; s < 2; ++s) {
            #pragma unroll
            for (int j = 0; j < 8; ++j) {
                const int q = s * 32 + quad * 8 + j;
                const float x = zb[(size_t)q * N_ + nn];
                zsq = fmaf(x, x, zsq);
                afrag[u][s][j] = f2bf(-2.f * x);   // exact pow2 scale
            }
        }
    }

    f32x4 best0 = {1e30f, 1e30f, 1e30f, 1e30f};
    f32x4 best1 = best0;

    // B source: codeword row (t*16 + n16), dims quad*8..+7 and 32+quad*8..+7
    const float* ebase = emb + n16 * Q_ + quad * 8;
    float4 c0a = *(const float4*)(ebase);
    float4 c0b = *(const float4*)(ebase + 4);
    float4 c1a = *(const float4*)(ebase + 32);
    float4 c1b = *(const float4*)(ebase + 36);

    for (int t = 0; t < 32; ++t) {
        float4 x0a = c0a, x0b = c0b, x1a = c1a, x1b = c1b;
        if (t < 31) {                         // prefetch next tile (wave-uniform branch)
            const float* np = ebase + (t + 1) * 16 * Q_;
            x0a = *(const float4*)(np);
            x0b = *(const float4*)(np + 4);
            x1a = *(const float4*)(np + 32);
            x1b = *(const float4*)(np + 36);
        }

        // e2 for codeword (t*16+n16): fp32 squares of this lane's 16 dims,
        // then sum across the 4 quads (lane bits 4,5).
        float p0 = 0.f, p1 = 0.f;
        p0 = fmaf(c0a.x, c0a.x, p0); p1 = fmaf(c0a.y, c0a.y, p1);
        p0 = fmaf(c0a.z, c0a.z, p0); p1 = fmaf(c0a.w, c0a.w, p1);
        p0 = fmaf(c0b.x, c0b.x, p0); p1 = fmaf(c0b.y, c0b.y, p1);
        p0 = fmaf(c0b.z, c0b.z, p0); p1 = fmaf(c0b.w, c0b.w, p1);
        p0 = fmaf(c1a.x, c1a.x, p0); p1 = fmaf(c1a.y, c1a.y, p1);
        p0 = fmaf(c1a.z, c1a.z, p0); p1 = fmaf(c1a.w, c1a.w, p1);
        p0 = fmaf(c1b.x, c1b.x, p0); p1 = fmaf(c1b.y, c1b.y, p1);
        p0 = fmaf(c1b.z, c1b.z, p0); p1 = fmaf(c1b.w, c1b.w, p1);
        float p = p0 + p1;
        p += __shfl_xor(p, 16, 64);
        p += __shfl_xor(p, 32, 64);

        // trunc-pack current tile's fp32 into bf16 fragments (8 v_perm)
        union { bf16x8 v; unsigned u[4]; } B0, B1;
        B0.u[0] = pack2(c0a.x, c0a.y); B0.u[1] = pack2(c0a.z, c0a.w);
        B0.u[2] = pack2(c0b.x, c0b.y); B0.u[3] = pack2(c0b.z, c0b.w);
        B1.u[0] = pack2(c1a.x, c1a.y); B1.u[1] = pack2(c1a.z, c1a.w);
        B1.u[2] = pack2(c1b.x, c1b.y); B1.u[3] = pack2(c1b.z, c1b.w);

        const f32x4 ce2 = {p, p, p, p};
        f32x4 a0 = __builtin_amdgcn_mfma_f32_16x16x32_bf16(afrag[0][0], B0.v, ce2, 0, 0, 0);
        a0       = __builtin_amdgcn_mfma_f32_16x16x32_bf16(afrag[0][1], B1.v, a0,  0, 0, 0);
        f32x4 a1 = __builtin_amdgcn_mfma_f32_16x16x32_bf16(afrag[1][0], B0.v, ce2, 0, 0, 0);
        a1       = __builtin_amdgcn_mfma_f32_16x16x32_bf16(afrag[1][1], B1.v, a1,  0, 0, 0);
        #pragma unroll
        for (int r = 0; r < 4; ++r) {
            best0[r] = fminf(best0[r], a0[r]);
            best1[r] = fminf(best1[r], a1[r]);
        }
        c0a = x0a; c0b = x0b; c1a = x1a; c1b = x1b;
    }

    // min over the 16 codeword lanes (low 4 lane bits)
    #pragma unroll
    for (int m = 1; m < 16; m <<= 1) {
        #pragma unroll
        for (int r = 0; r < 4; ++r) {
            best0[r] = fminf(best0[r], __shfl_xor(best0[r], m, 64));
            best1[r] = fminf(best1[r], __shfl_xor(best1[r], m, 64));
        }
    }

    float val = 1.25f * zsq;                 // exact fp32 sum z^2 (this lane's elems)
    if (n16 == 0) {
        float s = 0.f;
        #pragma unroll
        for (int r = 0; r < 4; ++r) s += best0[r] + best1[r];
        val += 1.25f * s;
    }
    #pragma unroll
    for (int off = 32; off > 0; off >>= 1) val += __shfl_down(val, off, 64);
    if (lane == 0) atomicAdd(out, val);
}

// ---------------------------------------------------------------------------
// CE: block = 256 consecutive n (one b), lane owns 4 n (float4 loads, 1KB/instr
// per wave), wave w covers class quarter [64w,64w+64). No-max sum(exp).
// ---------------------------------------------------------------------------
__global__ __launch_bounds__(256) void ce_kernel(const float* __restrict__ qp,
                                                 const int* __restrict__ tgt,
                                                 float* __restrict__ out)
{
    __shared__ f32x4 part[4][64];
    const int lane = threadIdx.x & 63;
    const int w    = threadIdx.x >> 6;
    const int base = blockIdx.x * 256;       // flat item base, 256-aligned
    const int b    = base >> 13;
    const int n0   = base & (N_ - 1);
    const float* qpn = qp + (size_t)b * C_ * N_ + n0 + lane * 4;

    f32x4 acc0 = {0.f, 0.f, 0.f, 0.f}, acc1 = acc0;
    #pragma unroll 4
    for (int c = w * 64; c < w * 64 + 64; c += 2) {
        const float4 v0 = *(const float4*)(qpn + (size_t)c * N_);
        const float4 v1 = *(const float4*)(qpn + (size_t)(c + 1) * N_);
        acc0[0] += __expf(v0.x); acc0[1] += __expf(v0.y);
        acc0[2] += __expf(v0.z); acc0[3] += __expf(v0.w);
        acc1[0] += __expf(v1.x); acc1[1] += __expf(v1.y);
        acc1[2] += __expf(v1.z); acc1[3] += __expf(v1.w);
    }
    part[w][lane] = acc0 + acc1;
    __syncthreads();

    if (w == 0) {
        const f32x4 s = (part[0][lane] + part[1][lane]) +
                        (part[2][lane] + part[3][lane]);
        const int i0 = base + lane * 4;
        float loss = 0.f;
        #pragma unroll
        for (int j = 0; j < 4; ++j) {
            const int t = tgt[i0 + j];
            const float xt = qpn[(size_t)t * N_ + j];   // qp[b, t, n0+lane*4+j]
            loss += __logf(s[j]) - xt;
        }
        #pragma unroll
        for (int off = 32; off > 0; off >>= 1) loss += __shfl_down(loss, off, 64);
        if (lane == 0) atomicAdd(out, loss);
    }
}

extern "C" void kernel_launch(void* const* d_in, const int* in_sizes, int n_in,
                              void* d_out, int out_size, void* d_ws, size_t ws_size,
                              hipStream_t stream) {
    const float* ze  = (const float*)d_in[0];
    const float* emb = (const float*)d_in[1];
    const float* qp  = (const float*)d_in[2];
    const int*   tgt = (const int*)d_in[3];
    float* out = (float*)d_out;

    hipMemsetAsync(out, 0, sizeof(float), stream);

    ce_kernel<<<(B_ * N_) / 256, 256, 0, stream>>>(qp, tgt, out);
    vq_kernel<<<(B_ * N_) / 128, 256, 0, stream>>>(ze, emb, out);
}

// Round 10
// 159.769 us; speedup vs baseline: 1.0637x; 1.0637x over previous
//
#include <hip/hip_runtime.h>
#include <math.h>

#define GAMMA 0.25f
constexpr int B_ = 8, Q_ = 64, N_ = 8192, K_ = 512, C_ = 256;

typedef __attribute__((ext_vector_type(8))) short bf16x8;
typedef __attribute__((ext_vector_type(4))) float f32x4;

static __device__ inline short f2bf(float x) {   // RNE float->bf16 bits
    union { float f; unsigned u; } v; v.f = x;
    unsigned r = (v.u + 0x7fffu + ((v.u >> 16) & 1u)) >> 16;
    return (short)r;
}
// pack trunc(lo),trunc(hi) bf16 into one dword via v_perm_b32 (1 instr)
static __device__ inline unsigned pack2(float lo, float hi) {
    return __builtin_amdgcn_perm(__float_as_uint(hi), __float_as_uint(lo), 0x07060302u);
}

// ---------------------------------------------------------------------------
// Fused kernel, grid = 1536 blocks: bid%3==2 -> VQ (512 blocks, 128 items
// each), else CE (1024 blocks, 64 items each). Interleaved so latency-bound
// VQ waves co-reside with BW-bound CE waves on every CU.
// ---------------------------------------------------------------------------
__global__ __launch_bounds__(256, 2) void fused_kernel(
    const float* __restrict__ ze, const float* __restrict__ emb,
    const float* __restrict__ qp, const int* __restrict__ tgt,
    float* __restrict__ out)
{
    __shared__ float smem[1024];   // 4 KB. CE: f32x4 part[64] (=1 KB). VQ: e2[512].
    const int bid  = blockIdx.x;
    const int tid  = threadIdx.x;
    const int lane = tid & 63;
    const int w    = tid >> 6;

    if (bid % 3 != 2) {
        // =============================== CE ===============================
        // block = 64 items x 256 classes. wave w: class quarter [64w,64w+64).
        // thread: g = lane&15 owns items 4g..4g+3 (float4); c0 = lane>>4 picks
        // 16 classes (c = 64w + 16c0 + j). Per load instr: 4 class rows x
        // 256 B contiguous = 1 KB coalesced.
        const int cid  = (bid / 3) * 2 + (bid % 3);   // 0..1023
        const int base = cid * 64;                    // flat item base, 64-aligned
        const int b    = base >> 13;
        const int n0   = base & (N_ - 1);
        const int g    = lane & 15;
        const int c0   = lane >> 4;
        const float* qpn = qp + (size_t)b * C_ * N_ + n0 + g * 4;

        f32x4 acc = {0.f, 0.f, 0.f, 0.f};
        const int cbase = w * 64 + c0 * 16;
        #pragma unroll
        for (int j = 0; j < 16; ++j) {
            const float4 v = *(const float4*)(qpn + (size_t)(cbase + j) * N_);
            acc[0] += __expf(v.x); acc[1] += __expf(v.y);
            acc[2] += __expf(v.z); acc[3] += __expf(v.w);
        }
        #pragma unroll
        for (int r = 0; r < 4; ++r) {                 // sum over c0 (lane bits 4,5)
            acc[r] += __shfl_xor(acc[r], 16, 64);
            acc[r] += __shfl_xor(acc[r], 32, 64);
        }
        f32x4* part = (f32x4*)smem;                   // part[w*16+g]
        if (c0 == 0) part[w * 16 + g] = acc;
        __syncthreads();

        if (w == 0) {
            float loss = 0.f;
            if (lane < 16) {                          // g = lane
                const f32x4 tot = (part[g] + part[16 + g]) +
                                  (part[32 + g] + part[48 + g]);
                #pragma unroll
                for (int j2 = 0; j2 < 4; ++j2) {
                    const int t = tgt[base + g * 4 + j2];
                    const float xt = qpn[(size_t)t * N_ + j2];
                    loss += __logf(tot[j2]) - xt;
                }
            }
            #pragma unroll
            for (int off = 32; off > 0; off >>= 1) loss += __shfl_down(loss, off, 64);
            if (lane == 0) atomicAdd(out, loss);
        }
    } else {
        // =============================== VQ ===============================
        const int vid  = bid / 3;                     // 0..511
        const int n16  = lane & 15;
        const int quad = lane >> 4;
        const int ib0  = vid * 128;                   // 128-aligned => b uniform
        const int b    = ib0 >> 13;
        const int n0   = ib0 & (N_ - 1);
        const float* zb = ze + (size_t)b * Q_ * N_;

        // e2 prologue: e2[r] = ||emb_r||^2 fp32, 2 rows/thread, into LDS.
        for (int r = tid; r < K_; r += 256) {
            const float4* er = (const float4*)(emb + r * Q_);
            float s0 = 0.f, s1 = 0.f;
            #pragma unroll
            for (int i = 0; i < 16; i += 2) {
                const float4 a = er[i], c = er[i + 1];
                s0 = fmaf(a.x, a.x, fmaf(a.y, a.y, fmaf(a.z, a.z, fmaf(a.w, a.w, s0))));
                s1 = fmaf(c.x, c.x, fmaf(c.y, c.y, fmaf(c.z, c.z, fmaf(c.w, c.w, s1))));
            }
            smem[r] = s0 + s1;
        }

        // A fragments: bf16(-2z) RNE + exact fp32 sum(z^2). Independent of LDS.
        bf16x8 afrag[2][2];
        float zsq = 0.f;
        #pragma unroll
        for (int u = 0; u < 2; ++u) {
            const int nn = n0 + u * 64 + w * 16 + n16;
            #pragma unroll
            for (int s = 0; s < 2; ++s) {
                #pragma unroll
                for (int j = 0; j < 8; ++j) {
                    const int q = s * 32 + quad * 8 + j;
                    const float x = zb[(size_t)q * N_ + nn];
                    zsq = fmaf(x, x, zsq);
                    afrag[u][s][j] = f2bf(-2.f * x);  // exact pow2 scale
                }
            }
        }
        __syncthreads();

        f32x4 best0 = {1e30f, 1e30f, 1e30f, 1e30f};
        f32x4 best1 = best0;

        // B tiles straight from fp32 emb (L2-hot), prefetched one ahead.
        const float* ebase = emb + n16 * Q_ + quad * 8;
        float4 c0a = *(const float4*)(ebase);
        float4 c0b = *(const float4*)(ebase + 4);
        float4 c1a = *(const float4*)(ebase + 32);
        float4 c1b = *(const float4*)(ebase + 36);

        for (int t = 0; t < 32; ++t) {
            float4 x0a = c0a, x0b = c0b, x1a = c1a, x1b = c1b;
            if (t < 31) {                             // wave-uniform prefetch branch
                const float* np = ebase + (t + 1) * 16 * Q_;
                x0a = *(const float4*)(np);
                x0b = *(const float4*)(np + 4);
                x1a = *(const float4*)(np + 32);
                x1b = *(const float4*)(np + 36);
            }
            const float p = smem[t * 16 + n16];       // broadcast ds_read, off crit path

            union { bf16x8 v; unsigned u[4]; } B0, B1;
            B0.u[0] = pack2(c0a.x, c0a.y); B0.u[1] = pack2(c0a.z, c0a.w);
            B0.u[2] = pack2(c0b.x, c0b.y); B0.u[3] = pack2(c0b.z, c0b.w);
            B1.u[0] = pack2(c1a.x, c1a.y); B1.u[1] = pack2(c1a.z, c1a.w);
            B1.u[2] = pack2(c1b.x, c1b.y); B1.u[3] = pack2(c1b.z, c1b.w);

            const f32x4 ce2 = {p, p, p, p};
            f32x4 a0 = __builtin_amdgcn_mfma_f32_16x16x32_bf16(afrag[0][0], B0.v, ce2, 0, 0, 0);
            a0       = __builtin_amdgcn_mfma_f32_16x16x32_bf16(afrag[0][1], B1.v, a0,  0, 0, 0);
            f32x4 a1 = __builtin_amdgcn_mfma_f32_16x16x32_bf16(afrag[1][0], B0.v, ce2, 0, 0, 0);
            a1       = __builtin_amdgcn_mfma_f32_16x16x32_bf16(afrag[1][1], B1.v, a1,  0, 0, 0);
            #pragma unroll
            for (int r = 0; r < 4; ++r) {
                best0[r] = fminf(best0[r], a0[r]);
                best1[r] = fminf(best1[r], a1[r]);
            }
            c0a = x0a; c0b = x0b; c1a = x1a; c1b = x1b;
        }

        // min over the 16 codeword lanes (low 4 lane bits)
        #pragma unroll
        for (int m = 1; m < 16; m <<= 1) {
            #pragma unroll
            for (int r = 0; r < 4; ++r) {
                best0[r] = fminf(best0[r], __shfl_xor(best0[r], m, 64));
                best1[r] = fminf(best1[r], __shfl_xor(best1[r], m, 64));
            }
        }

        float val = 1.25f * zsq;
        if (n16 == 0) {
            float s = 0.f;
            #pragma unroll
            for (int r = 0; r < 4; ++r) s += best0[r] + best1[r];
            val += 1.25f * s;
        }
        #pragma unroll
        for (int off = 32; off > 0; off >>= 1) val += __shfl_down(val, off, 64);
        if (lane == 0) atomicAdd(out, val);
    }
}

extern "C" void kernel_launch(void* const* d_in, const int* in_sizes, int n_in,
                              void* d_out, int out_size, void* d_ws, size_t ws_size,
                              hipStream_t stream) {
    const float* ze  = (const float*)d_in[0];
    const float* emb = (const float*)d_in[1];
    const float* qp  = (const float*)d_in[2];
    const int*   tgt = (const int*)d_in[3];
    float* out = (float*)d_out;

    hipMemsetAsync(out, 0, sizeof(float), stream);

    fused_kernel<<<1536, 256, 0, stream>>>(ze, emb, qp, tgt, out);
}